// Round 14
// baseline (373.527 us; speedup 1.0000x reference)
//
#include <hip/hip_runtime.h>
#include <stdint.h>

// DCNv2 x3 for MI355X. fp32 I/O, fp16 internal + MFMA f16.
// R23 = R22 (best, 364.4us) + BM=128 goffs tile for CIN>=128.
//       goffs<512,3> ideal is ~18us but ran ~45: M=64xN=32 tile = only
//       4 MFMA/wave/staging (~80cy) vs ~500cy fixed staging overhead
//       (barrier+ds_read latency+issue). N is capped at 32 (om width);
//       M doubled to 128 -> 8 MFMA/wave/staging, same barrier count, same
//       A/B traffic (M-split partitions the gather). LDS 45KB (2 blk/CU ok),
//       est ~130-150 VGPR spill-free (named-local pattern, R18-proven).
//       Grid (3*288)=864: z-fold stays bijective (864%8==0, 108%3==0).
//       Everything else R22-verbatim.

#define HH 96
#define WW 96
#define BBATCH 4
#define HWP (HH*WW)        // 9216
#define PTOT (BBATCH*HWP)  // 36864

typedef _Float16 f16x8 __attribute__((ext_vector_type(8)));
typedef _Float16 h2    __attribute__((ext_vector_type(2)));
typedef float f32x4 __attribute__((ext_vector_type(4)));

union U16x8 { uint4 q; _Float16 h[8]; h2 v[4]; };
union UB    { uint4 q; f16x8 f; };
union UH4   { uint2 d; _Float16 h[4]; };

__device__ __forceinline__ void barrier_nodrain(){
  asm volatile("s_waitcnt lgkmcnt(0)" ::: "memory");
  __builtin_amdgcn_s_barrier();
  __builtin_amdgcn_sched_barrier(0);
}

// ---- NCHW(f32, C=64) -> NHWC(f16) ----
__global__ void k_nchw2nhwc(const float* __restrict__ in, _Float16* __restrict__ out){
  __shared__ float t[32][33];
  int b = blockIdx.z;
  int p0 = blockIdx.x*32, c0 = blockIdx.y*32;
  int tx = threadIdx.x, ty = threadIdx.y; // 32x8
  #pragma unroll
  for(int i=0;i<32;i+=8)
    t[ty+i][tx] = in[((size_t)(b*64 + c0+ty+i))*HWP + p0+tx];
  __syncthreads();
  #pragma unroll
  for(int i=0;i<32;i+=8)
    out[((size_t)(b*HWP + p0+ty+i))*64 + c0+tx] = (_Float16)t[tx][ty+i];
}

// ---- fused weight transforms ----
template<int CIN,int COUT>
__global__ void k_twx(const float* __restrict__ ow, const float* __restrict__ w,
                      _Float16* __restrict__ owT, _Float16* __restrict__ wTf){
  int i = blockIdx.x*256 + threadIdx.x;
  constexpr int N1 = 9*32*CIN;
  constexpr int N2 = 9*COUT*CIN;
  if(i < N1){
    int c = i % CIN; int j = (i/CIN)&31; int k = i/(CIN*32);
    owT[i] = (j<27) ? (_Float16)ow[((size_t)(j*CIN + c))*9 + k] : (_Float16)0.f;
  } else if(i < N1+N2){
    int i2 = i - N1;
    int c = i2 % CIN; int o = (i2/CIN)%COUT; int k = i2/(CIN*COUT);
    int g = c>>5, quad = (c>>3)&3, j = c&7;
    int ob = o>>4, l15 = o&15;
    size_t dst = ((((size_t)k*(CIN/32) + g)*(COUT/16) + ob)*64 + quad*16 + l15)*8 + j;
    wTf[dst] = (_Float16)w[((size_t)(o*CIN + c))*9 + k];
  }
}

// ---- offset conv GEMM, NT taps per block.
//      CIN>=128: BM=128 pipelined spill-free + z-fold + nodrain barriers.
//      CIN==64: R6 verbatim (BM=64, blockIdx.y = tap-group). ----
template<int CIN,int NT>
__launch_bounds__(256,2)
__global__ void k_goffs(const _Float16* __restrict__ xin, const _Float16* __restrict__ owT,
                        float* __restrict__ om){
  int t = threadIdx.x;
  int lane = t&63, wave = t>>6;
  int quad = lane>>4, l15 = lane&15;

  if constexpr (CIN >= 128){
    constexpr int NZ = (NT==3) ? 3 : 1;   // gridDim.x%8==0, (gridDim.x/8)%NZ==0
    int bx = blockIdx.x;
    int q = bx>>3, r = bx&7;
    int z = q - (q/NZ)*NZ;                // q % NZ
    int lin = r*((gridDim.x>>3)/NZ) + q/NZ;
    int pos0 = lin*128;
    int K0 = z*NT;
    float* omo = om + (size_t)z*PTOT*32;

    constexpr int SPT = CIN/64;     // stagings per tap
    constexpr int S = NT*SPT;       // total stagings (even)
    __shared__ __align__(16) _Float16 As[2][128*72];
    __shared__ __align__(16) _Float16 Bs[2][32*72];
    int pa = t>>1, ca = (t&1)*32;   // A: 128 pos x 32 ch/thread (4 uint4)
    int jb = t>>3, cb = (t&7)*8;    // B: 32 rows x 8 ch/thread
    int P = pos0 + pa;
    int b = P/HWP, rem = P%HWP;
    int y = rem/WW, x = rem%WW;
    const _Float16* baseA = xin + (size_t)b*HWP*CIN + ca;
    const uint4 zz = make_uint4(0,0,0,0);
    f32x4 acc[2][2] = {};           // [mi][ni]: wave rows wave*32 + mi*16
    int ofsC, ofsN = 0; bool vldC, vldN = false; int ktC, ktN = 0;
    {
      int iy = y + K0/3 - 1, ix = x + K0%3 - 1;
      vldC = (iy>=0)&&(iy<HH)&&(ix>=0)&&(ix<WW);
      int cy = min(max(iy,0),HH-1), cx = min(max(ix,0),WW-1);
      ofsC = (cy*WW+cx)*CIN; ktC = K0;
    }
    // staging 0 direct to LDS[0]
    {
      uint4 a0 = vldC ? *(const uint4*)(baseA + ofsC)      : zz;
      uint4 a1 = vldC ? *(const uint4*)(baseA + ofsC + 8)  : zz;
      uint4 a2 = vldC ? *(const uint4*)(baseA + ofsC + 16) : zz;
      uint4 a3 = vldC ? *(const uint4*)(baseA + ofsC + 24) : zz;
      uint4 bv = *(const uint4*)(owT + ((size_t)ktC*32 + jb)*CIN + cb);
      *(uint4*)&As[0][pa*72 + ca]      = a0;
      *(uint4*)&As[0][pa*72 + ca + 8]  = a1;
      *(uint4*)&As[0][pa*72 + ca + 16] = a2;
      *(uint4*)&As[0][pa*72 + ca + 24] = a3;
      *(uint4*)&Bs[0][jb*72 + cb]      = bv;
    }
    // prefetch staging 1 into parity-A regs (same tap, c0=64; SPT>=2)
    uint4 nA0 = vldC ? *(const uint4*)(baseA + ofsC + 64)      : zz;
    uint4 nA1 = vldC ? *(const uint4*)(baseA + ofsC + 64 + 8)  : zz;
    uint4 nA2 = vldC ? *(const uint4*)(baseA + ofsC + 64 + 16) : zz;
    uint4 nA3 = vldC ? *(const uint4*)(baseA + ofsC + 64 + 24) : zz;
    uint4 nAb = *(const uint4*)(owT + ((size_t)ktC*32 + jb)*CIN + 64 + cb);
    uint4 nB0, nB1, nB2, nB3, nBb;
    int buf = 0;

    #pragma unroll 1
    for(int ss=0; ss<S; ss+=2){
      // ======== staging ss (even): parity-A regs hold staging ss+1 ========
      {
        const int s = ss;
        barrier_nodrain();                // As/Bs[buf] visible; loads ride
        if(s > 0 && (s % SPT) == 0){ ofsC=ofsN; vldC=vldN; ktC=ktN; }
        if(s+2 < S){
          int sm2 = (s+2) % SPT;
          if(sm2 == 0){
            int k = K0 + (s+2)/SPT;
            int iy = y + k/3 - 1, ix = x + k%3 - 1;
            vldN = (iy>=0)&&(iy<HH)&&(ix>=0)&&(ix<WW);
            int cy = min(max(iy,0),HH-1), cx = min(max(ix,0),WW-1);
            ofsN = (cy*WW+cx)*CIN; ktN = k;
          }
          bool useN = (sm2 < 2);
          int ofs = useN ? ofsN : ofsC;
          bool vld = useN ? vldN : vldC;
          int kt  = useN ? ktN  : ktC;
          int c0 = sm2*64;
          nB0 = vld ? *(const uint4*)(baseA + ofs + c0)      : zz;
          nB1 = vld ? *(const uint4*)(baseA + ofs + c0 + 8)  : zz;
          nB2 = vld ? *(const uint4*)(baseA + ofs + c0 + 16) : zz;
          nB3 = vld ? *(const uint4*)(baseA + ofs + c0 + 24) : zz;
          nBb = *(const uint4*)(owT + ((size_t)kt*32 + jb)*CIN + c0 + cb);
        }
        #pragma unroll
        for(int mi=0;mi<2;mi++){
          UB af0, af1;
          af0.q = *(const uint4*)&As[buf][(wave*32 + mi*16 + l15)*72 + quad*8];
          af1.q = *(const uint4*)&As[buf][(wave*32 + mi*16 + l15)*72 + 32 + quad*8];
          #pragma unroll
          for(int ni=0;ni<2;ni++){
            UB bu0, bu1;
            bu0.q = *(const uint4*)&Bs[buf][(ni*16 + l15)*72 + quad*8];
            bu1.q = *(const uint4*)&Bs[buf][(ni*16 + l15)*72 + 32 + quad*8];
            acc[mi][ni] = __builtin_amdgcn_mfma_f32_16x16x32_f16(af0.f, bu0.f, acc[mi][ni], 0,0,0);
            acc[mi][ni] = __builtin_amdgcn_mfma_f32_16x16x32_f16(af1.f, bu1.f, acc[mi][ni], 0,0,0);
          }
        }
        if(s+1 < S){
          *(uint4*)&As[buf^1][pa*72 + ca]      = nA0;
          *(uint4*)&As[buf^1][pa*72 + ca + 8]  = nA1;
          *(uint4*)&As[buf^1][pa*72 + ca + 16] = nA2;
          *(uint4*)&As[buf^1][pa*72 + ca + 24] = nA3;
          *(uint4*)&Bs[buf^1][jb*72 + cb]      = nAb;
        }
        buf ^= 1;
      }
      // ======== staging ss+1 (odd): parity-B regs hold staging ss+2 ========
      {
        const int s = ss+1;
        barrier_nodrain();
        if((s % SPT) == 0){ ofsC=ofsN; vldC=vldN; ktC=ktN; }
        if(s+2 < S){
          int sm2 = (s+2) % SPT;
          if(sm2 == 0){
            int k = K0 + (s+2)/SPT;
            int iy = y + k/3 - 1, ix = x + k%3 - 1;
            vldN = (iy>=0)&&(iy<HH)&&(ix>=0)&&(ix<WW);
            int cy = min(max(iy,0),HH-1), cx = min(max(ix,0),WW-1);
            ofsN = (cy*WW+cx)*CIN; ktN = k;
          }
          bool useN = (sm2 < 2);
          int ofs = useN ? ofsN : ofsC;
          bool vld = useN ? vldN : vldC;
          int kt  = useN ? ktN  : ktC;
          int c0 = sm2*64;
          nA0 = vld ? *(const uint4*)(baseA + ofs + c0)      : zz;
          nA1 = vld ? *(const uint4*)(baseA + ofs + c0 + 8)  : zz;
          nA2 = vld ? *(const uint4*)(baseA + ofs + c0 + 16) : zz;
          nA3 = vld ? *(const uint4*)(baseA + ofs + c0 + 24) : zz;
          nAb = *(const uint4*)(owT + ((size_t)kt*32 + jb)*CIN + c0 + cb);
        }
        #pragma unroll
        for(int mi=0;mi<2;mi++){
          UB af0, af1;
          af0.q = *(const uint4*)&As[buf][(wave*32 + mi*16 + l15)*72 + quad*8];
          af1.q = *(const uint4*)&As[buf][(wave*32 + mi*16 + l15)*72 + 32 + quad*8];
          #pragma unroll
          for(int ni=0;ni<2;ni++){
            UB bu0, bu1;
            bu0.q = *(const uint4*)&Bs[buf][(ni*16 + l15)*72 + quad*8];
            bu1.q = *(const uint4*)&Bs[buf][(ni*16 + l15)*72 + 32 + quad*8];
            acc[mi][ni] = __builtin_amdgcn_mfma_f32_16x16x32_f16(af0.f, bu0.f, acc[mi][ni], 0,0,0);
            acc[mi][ni] = __builtin_amdgcn_mfma_f32_16x16x32_f16(af1.f, bu1.f, acc[mi][ni], 0,0,0);
          }
        }
        if(s+1 < S){
          *(uint4*)&As[buf^1][pa*72 + ca]      = nB0;
          *(uint4*)&As[buf^1][pa*72 + ca + 8]  = nB1;
          *(uint4*)&As[buf^1][pa*72 + ca + 16] = nB2;
          *(uint4*)&As[buf^1][pa*72 + ca + 24] = nB3;
          *(uint4*)&Bs[buf^1][jb*72 + cb]      = nBb;
        }
        buf ^= 1;
      }
      // one barrier/staging: writes target buf^1, re-written only after two
      // more barriers -> WAR-safe (R10 proof).
    }
    // epilogue (BM=128): wave rows wave*32 + mi*16
    #pragma unroll
    for(int mi=0;mi<2;mi++)
      #pragma unroll
      for(int ni=0;ni<2;ni++)
        #pragma unroll
        for(int r2=0;r2<4;r2++){
          int row = wave*32 + mi*16 + quad*4 + r2;
          omo[(size_t)(pos0+row)*32 + ni*16 + l15] = acc[mi][ni][r2];
        }
  } else {
    // ---- R6 verbatim path (CIN==64, BM=64) ----
    int pos0 = blockIdx.x*64;
    int K0 = blockIdx.y*NT;
    float* omo = om + (size_t)blockIdx.y*PTOT*32;
    __shared__ __align__(16) _Float16 As[64*40];
    __shared__ __align__(16) _Float16 Bs[32*40];
    f32x4 acc[2] = {};
    int pa = t>>2, ca = (t&3)*8;
    int P = pos0 + pa;
    int b = P/HWP, rem = P%HWP;
    int y = rem/WW, x = rem%WW;
    #pragma unroll 1
    for(int k=K0;k<K0+NT;k++){
      int iy = y + k/3 - 1, ix = x + k%3 - 1;
      bool valid = (iy>=0)&&(iy<HH)&&(ix>=0)&&(ix<WW);
      const _Float16* src = xin + (((size_t)b*HWP + iy*WW + ix)*CIN) + ca;
      #pragma unroll 1
      for(int c0=0;c0<CIN;c0+=32){
        uint4 av = make_uint4(0,0,0,0);
        if(valid) av = *(const uint4*)(src + c0);
        *(uint4*)&As[pa*40 + ca] = av;
        if(t < 128){
          int j = t>>2;
          *(uint4*)&Bs[j*40 + ca] = *(const uint4*)(owT + ((size_t)k*32 + j)*CIN + c0 + ca);
        }
        __syncthreads();
        UB afu; afu.q = *(const uint4*)&As[(wave*16 + l15)*40 + quad*8];
        #pragma unroll
        for(int ni=0;ni<2;ni++){
          UB bu; bu.q = *(const uint4*)&Bs[(ni*16 + l15)*40 + quad*8];
          acc[ni] = __builtin_amdgcn_mfma_f32_16x16x32_f16(afu.f, bu.f, acc[ni], 0,0,0);
        }
        __syncthreads();
      }
    }
    #pragma unroll
    for(int ni=0;ni<2;ni++)
      #pragma unroll
      for(int r2=0;r2<4;r2++){
        int row = wave*16 + quad*4 + r2;
        omo[(size_t)(pos0+row)*32 + ni*16 + l15] = acc[ni][r2];
      }
  }
}

// ---- per-(p,k) sampling params; sums NS om slabs (R6 verbatim) ----
template<int NS>
__global__ void k_prep(const float* __restrict__ om, const float* __restrict__ ob,
                       float* __restrict__ pym){
  int i = blockIdx.x*256 + threadIdx.x;
  if(i >= PTOT*9) return;
  int k = i%9, p = i/9;
  int rem = p%HWP;
  int y = rem/WW, x = rem%WW;
  float oy=0.f, ox=0.f, mm=0.f;
  #pragma unroll
  for(int s=0;s<NS;s++){
    const float* o = om + (size_t)s*PTOT*32 + (size_t)p*32;
    oy += o[2*k]; ox += o[2*k+1]; mm += o[18+k];
  }
  oy += ob[2*k]; ox += ob[2*k+1]; mm += ob[18+k];
  float m = 1.f/(1.f + expf(-mm));
  pym[(size_t)i*3+0] = (float)(y + k/3 - 1) + oy;
  pym[(size_t)i*3+1] = (float)(x + k%3 - 1) + ox;
  pym[(size_t)i*3+2] = m;
}

// ---- main DCN GEMM: R21 structure (pipeline + diet + z-fold + nodrain).
//      SPT>1 (CIN=512): 2-deep corner prefetch. SPT==1: 1-deep.
//      MODE 0: 9 taps, f16 NHWC out (+bias).
//      MODE 1: 3 taps (z folded in bx), fp32 partial out (no bias).
//      MODE 2: 3 taps (z folded in bx), f16 partial out (no bias).
template<int CIN,int COUT,int BN,int MODE>
__launch_bounds__(256,2)
__global__ void k_gmain(const _Float16* __restrict__ xin, const float* __restrict__ pym,
                        const _Float16* __restrict__ wTf, const float* __restrict__ bias,
                        void* __restrict__ outv){
  constexpr int NW = BN/4;      // per-wave N width
  constexpr int NF = NW/16;     // n-frags per wave
  constexpr int KG = CIN/32;    // K-groups
  constexpr int OB = COUT/16;   // o-blocks
  constexpr int SPT = CIN/64;   // stagings per tap
  constexpr int NZ = (MODE>=1) ? 3 : 1;   // z-slabs folded into grid.x
  constexpr int KN = (MODE>=1) ? 3 : 9;
  constexpr int S = KN*SPT;     // total stagings
  __shared__ __align__(16) _Float16 As[2][64*72];   // 64 pos x 64ch, stride 72
  int bx = blockIdx.x;
  // bijective XCD swizzle + z-fold: gridDim.x % 8 == 0, (gridDim.x/8) % NZ == 0
  int q = bx>>3, r = bx&7;
  int z = q - (q/NZ)*NZ;                       // q % NZ
  int lin = r*((gridDim.x>>3)/NZ) + q/NZ;      // contiguous chunk per XCD
  int pos0 = lin*64;
  int o0 = blockIdx.y*BN;
  int K0 = (MODE>=1) ? z*3 : 0;
  int t = threadIdx.x;
  int lane = t&63, wave = t>>6;
  int quad = lane>>4, l15 = lane&15;
  f32x4 acc[4][NF] = {};
  int pa = t>>2, ca = (t&3)*16;   // 16 channels per thread
  int P = pos0 + pa;
  int b = P/HWP;
  const _Float16* base = xin + (size_t)b*HWP*CIN + ca;
  const uint4* wf = (const uint4*)wTf;
  int obBase = (o0>>4) + wave*NF;

  auto tapParams = [&](int k, h2* W, int* oc){
    const float* pp = pym + ((size_t)P*9 + k)*3;
    float py = pp[0], px = pp[1], mk = pp[2];
    float y0f = floorf(py), x0f = floorf(px);
    float wy = py - y0f, wx = px - x0f;
    int iy0 = (int)y0f, ix0 = (int)x0f;
    int iy1 = iy0+1, ix1 = ix0+1;
    bool vy0 = (iy0>=0)&&(iy0<HH), vy1 = (iy1>=0)&&(iy1<HH);
    bool vx0 = (ix0>=0)&&(ix0<WW), vx1 = (ix1>=0)&&(ix1<WW);
    float w00 = (vy0&&vx0) ? (1.f-wy)*(1.f-wx)*mk : 0.f;
    float w01 = (vy0&&vx1) ? (1.f-wy)*wx*mk      : 0.f;
    float w10 = (vy1&&vx0) ? wy*(1.f-wx)*mk      : 0.f;
    float w11 = (vy1&&vx1) ? wy*wx*mk            : 0.f;
    int cy0 = min(max(iy0,0),HH-1), cy1 = min(max(iy1,0),HH-1);
    int cx0 = min(max(ix0,0),WW-1), cx1 = min(max(ix1,0),WW-1);
    W[0] = h2{(_Float16)w00,(_Float16)w00};
    W[1] = h2{(_Float16)w01,(_Float16)w01};
    W[2] = h2{(_Float16)w10,(_Float16)w10};
    W[3] = h2{(_Float16)w11,(_Float16)w11};
    oc[0] = (cy0*WW+cx0)*CIN;
    oc[1] = (cy0*WW+cx1)*CIN;
    oc[2] = (cy1*WW+cx0)*CIN;
    oc[3] = (cy1*WW+cx1)*CIN;
  };

  // B(s) linear address: idx = (K0 + s/SPT)*KG + 2*(s%SPT) = K0*KG + 2*s
  uint4 Bq[2][NF];
  const uint4* wB = wf + (size_t)(K0*KG)*OB*64 + lane;
  int buf = 0;

  if constexpr (SPT > 1){
    // ================= 2-deep corner-prefetch path (CIN=512) =================
    h2 Wcur[4], Wnxt[4];
    int ocCur[4], ocNxt[4];
    tapParams(K0, Wcur, ocCur);
    U16x8 ncA[4][2], ncB[4][2];
    // prologue: produce staging 0; load B(0); issue corners(1) -> ncA
    {
      U16x8 c0v[4][2];
      #pragma unroll
      for(int c=0;c<4;c++){
        const _Float16* pp = base + ocCur[c];
        c0v[c][0].q = *(const uint4*)(pp);
        c0v[c][1].q = *(const uint4*)(pp + 8);
      }
      #pragma unroll
      for(int ks=0;ks<2;ks++)
        #pragma unroll
        for(int ni=0;ni<NF;ni++)
          Bq[ks][ni] = wB[(size_t)ks*OB*64 + (size_t)(obBase+ni)*64];
      wB += 2*OB*64;
      U16x8 rr0, rr1;
      #pragma unroll
      for(int j=0;j<4;j++){
        rr0.v[j] = c0v[0][0].v[j]*Wcur[0] + c0v[1][0].v[j]*Wcur[1] + c0v[2][0].v[j]*Wcur[2] + c0v[3][0].v[j]*Wcur[3];
        rr1.v[j] = c0v[0][1].v[j]*Wcur[0] + c0v[1][1].v[j]*Wcur[1] + c0v[2][1].v[j]*Wcur[2] + c0v[3][1].v[j]*Wcur[3];
      }
      *(uint4*)&As[0][pa*72 + ca]     = rr0.q;
      *(uint4*)&As[0][pa*72 + ca + 8] = rr1.q;
      // corners for staging 1 (tap 0, c0=64)
      #pragma unroll
      for(int c=0;c<4;c++){
        const _Float16* pp = base + ocCur[c] + 64;
        ncA[c][0].q = *(const uint4*)(pp);
        ncA[c][1].q = *(const uint4*)(pp + 8);
      }
    }

    auto stage = [&](int s, U16x8 (&ncC)[4][2], U16x8 (&ncN)[4][2]){
      barrier_nodrain();                   // As[buf] visible; loads ride
      bool more  = (s+1 < S);
      bool more2 = (s+2 < S);
      if(s > 0 && (s % SPT) == 0){
        #pragma unroll
        for(int j=0;j<4;j++){ Wcur[j]=Wnxt[j]; ocCur[j]=ocNxt[j]; }
      }
      if(more2){
        int sm2 = (s+2) % SPT;
        if(sm2 == 0) tapParams(K0 + (s+2)/SPT, Wnxt, ocNxt);
        bool useNxt = (sm2 < 2);
        int ocS[4];
        #pragma unroll
        for(int c=0;c<4;c++) ocS[c] = useNxt ? ocNxt[c] : ocCur[c];
        int c0 = sm2*64;
        #pragma unroll
        for(int c=0;c<4;c++){
          const _Float16* pp = base + ocS[c] + c0;
          ncN[c][0].q = *(const uint4*)(pp);
          ncN[c][1].q = *(const uint4*)(pp + 8);
        }
      }
      UB afu[2][4];
      #pragma unroll
      for(int ks=0;ks<2;ks++)
        #pragma unroll
        for(int mi=0;mi<4;mi++)
          afu[ks][mi].q = *(const uint4*)&As[buf][(mi*16 + l15)*72 + ks*32 + quad*8];
      #pragma unroll
      for(int ks=0;ks<2;ks++)
        #pragma unroll
        for(int ni=0;ni<NF;ni++){
          UB bu; bu.q = Bq[ks][ni];
          #pragma unroll
          for(int mi=0;mi<4;mi++)
            acc[mi][ni] = __builtin_amdgcn_mfma_f32_16x16x32_f16(afu[ks][mi].f, bu.f, acc[mi][ni], 0,0,0);
        }
      if(more){
        #pragma unroll
        for(int ks=0;ks<2;ks++)
          #pragma unroll
          for(int ni=0;ni<NF;ni++)
            Bq[ks][ni] = wB[(size_t)ks*OB*64 + (size_t)(obBase+ni)*64];
        wB += 2*OB*64;
        bool lerpNxt = (((s+1) % SPT) == 0);
        h2 Wl[4];
        #pragma unroll
        for(int j=0;j<4;j++) Wl[j] = lerpNxt ? Wnxt[j] : Wcur[j];
        U16x8 rr0, rr1;
        #pragma unroll
        for(int j=0;j<4;j++){
          rr0.v[j] = ncC[0][0].v[j]*Wl[0] + ncC[1][0].v[j]*Wl[1] + ncC[2][0].v[j]*Wl[2] + ncC[3][0].v[j]*Wl[3];
          rr1.v[j] = ncC[0][1].v[j]*Wl[0] + ncC[1][1].v[j]*Wl[1] + ncC[2][1].v[j]*Wl[2] + ncC[3][1].v[j]*Wl[3];
        }
        *(uint4*)&As[buf^1][pa*72 + ca]     = rr0.q;
        *(uint4*)&As[buf^1][pa*72 + ca + 8] = rr1.q;
      }
      buf ^= 1;
    };

    #pragma unroll 1
    for(int ss=0; ss<S; ss+=2){   // S even for all CIN=512 instantiations
      stage(ss,   ncA, ncB);
      stage(ss+1, ncB, ncA);
    }
  } else {
    // ================= R14 1-deep path (CIN=64, proven) =================
    h2 Wc[4]; int oc_[4];
    h2 Wn[4]; int ocn[4];
    tapParams(K0, Wc, oc_);
    {
      U16x8 nc[4][2];
      #pragma unroll
      for(int c=0;c<4;c++){
        const _Float16* pp = base + oc_[c];
        nc[c][0].q = *(const uint4*)(pp);
        nc[c][1].q = *(const uint4*)(pp + 8);
      }
      #pragma unroll
      for(int ks=0;ks<2;ks++)
        #pragma unroll
        for(int ni=0;ni<NF;ni++)
          Bq[ks][ni] = wB[(size_t)ks*OB*64 + (size_t)(obBase+ni)*64];
      wB += 2*OB*64;
      U16x8 rr0, rr1;
      #pragma unroll
      for(int j=0;j<4;j++){
        rr0.v[j] = nc[0][0].v[j]*Wc[0] + nc[1][0].v[j]*Wc[1] + nc[2][0].v[j]*Wc[2] + nc[3][0].v[j]*Wc[3];
        rr1.v[j] = nc[0][1].v[j]*Wc[0] + nc[1][1].v[j]*Wc[1] + nc[2][1].v[j]*Wc[2] + nc[3][1].v[j]*Wc[3];
      }
      *(uint4*)&As[0][pa*72 + ca]     = rr0.q;
      *(uint4*)&As[0][pa*72 + ca + 8] = rr1.q;
    }
    if(S>1) tapParams(K0+1, Wn, ocn);

    #pragma unroll 1
    for(int s=0;s<S;s++){
      __syncthreads();
      U16x8 nc[4][2];
      bool more = (s+1 < S);
      if(more){
        #pragma unroll
        for(int c=0;c<4;c++){ Wc[c]=Wn[c]; oc_[c]=ocn[c]; }
        #pragma unroll
        for(int c=0;c<4;c++){
          const _Float16* pp = base + oc_[c];
          nc[c][0].q = *(const uint4*)(pp);
          nc[c][1].q = *(const uint4*)(pp + 8);
        }
      }
      UB afu[2][4];
      #pragma unroll
      for(int ks=0;ks<2;ks++)
        #pragma unroll
        for(int mi=0;mi<4;mi++)
          afu[ks][mi].q = *(const uint4*)&As[buf][(mi*16 + l15)*72 + ks*32 + quad*8];
      #pragma unroll
      for(int ks=0;ks<2;ks++)
        #pragma unroll
        for(int ni=0;ni<NF;ni++){
          UB bu; bu.q = Bq[ks][ni];
          #pragma unroll
          for(int mi=0;mi<4;mi++)
            acc[mi][ni] = __builtin_amdgcn_mfma_f32_16x16x32_f16(afu[ks][mi].f, bu.f, acc[mi][ni], 0,0,0);
        }
      if(more){
        #pragma unroll
        for(int ks=0;ks<2;ks++)
          #pragma unroll
          for(int ni=0;ni<NF;ni++)
            Bq[ks][ni] = wB[(size_t)ks*OB*64 + (size_t)(obBase+ni)*64];
        wB += 2*OB*64;
        if(s+2 < S) tapParams(K0+s+2, Wn, ocn);
        U16x8 rr0, rr1;
        #pragma unroll
        for(int j=0;j<4;j++){
          rr0.v[j] = nc[0][0].v[j]*Wc[0] + nc[1][0].v[j]*Wc[1] + nc[2][0].v[j]*Wc[2] + nc[3][0].v[j]*Wc[3];
          rr1.v[j] = nc[0][1].v[j]*Wc[0] + nc[1][1].v[j]*Wc[1] + nc[2][1].v[j]*Wc[2] + nc[3][1].v[j]*Wc[3];
        }
        *(uint4*)&As[buf^1][pa*72 + ca]     = rr0.q;
        *(uint4*)&As[buf^1][pa*72 + ca + 8] = rr1.q;
      }
      buf ^= 1;
    }
  }

  #pragma unroll
  for(int mi=0;mi<4;mi++){
    #pragma unroll
    for(int ni=0;ni<NF;ni++){
      int col = o0 + wave*NW + ni*16 + l15;
      if(MODE==1){
        float* out = (float*)outv + (size_t)z*PTOT*COUT;
        #pragma unroll
        for(int r2=0;r2<4;r2++){
          int row = pos0 + mi*16 + quad*4 + r2;
          out[(size_t)row*COUT + col] = acc[mi][ni][r2];
        }
      } else if(MODE==2){
        _Float16* out = (_Float16*)outv + (size_t)z*PTOT*COUT;
        #pragma unroll
        for(int r2=0;r2<4;r2++){
          int row = pos0 + mi*16 + quad*4 + r2;
          out[(size_t)row*COUT + col] = (_Float16)acc[mi][ni][r2];
        }
      } else {
        float bo = bias[col];
        _Float16* out = (_Float16*)outv;
        #pragma unroll
        for(int r2=0;r2<4;r2++){
          int row = pos0 + mi*16 + quad*4 + r2;
          out[(size_t)row*COUT + col] = (_Float16)(acc[mi][ni][r2]+bo);
        }
      }
    }
  }
}

// ---- reduce 3 fp32 partial slabs -> f16 NHWC (+bias) ----
template<int COUT>
__global__ void k_redA(const float* __restrict__ part, const float* __restrict__ bias,
                       _Float16* __restrict__ out){
  int i4 = blockIdx.x*256 + threadIdx.x;
  constexpr int N4 = PTOT*COUT/4;
  if(i4 >= N4) return;
  const float4* p = (const float4*)part;
  float4 a = p[i4], b = p[i4 + N4], c = p[i4 + 2*N4];
  int col0 = (i4*4) & (COUT-1);
  float4 bi = *(const float4*)(bias + col0);
  UH4 r;
  r.h[0] = (_Float16)(a.x+b.x+c.x+bi.x);
  r.h[1] = (_Float16)(a.y+b.y+c.y+bi.y);
  r.h[2] = (_Float16)(a.z+b.z+c.z+bi.z);
  r.h[3] = (_Float16)(a.w+b.w+c.w+bi.w);
  *(uint2*)(out + (size_t)i4*4) = r.d;
}

// ---- reduce 3 f16 partial slabs [P][256] -> fp32 NCHW (+bias), LDS transpose ----
__global__ void k_redT(const _Float16* __restrict__ part, const float* __restrict__ bias,
                       float* __restrict__ out){
  __shared__ float t[32][33];
  constexpr int COUT = 256;
  constexpr size_t SL = (size_t)PTOT*COUT;
  int b = blockIdx.z;
  int p0 = blockIdx.x*32, c0 = blockIdx.y*32;
  int tx = threadIdx.x, ty = threadIdx.y; // 32x8
  #pragma unroll
  for(int i=0;i<32;i+=8){
    size_t idx = ((size_t)(b*HWP + p0+ty+i))*COUT + c0+tx;
    t[ty+i][tx] = (float)part[idx] + (float)part[idx+SL] + (float)part[idx+2*SL];
  }
  __syncthreads();
  #pragma unroll
  for(int i=0;i<32;i+=8)
    out[((size_t)(b*COUT + c0+ty+i))*HWP + p0+tx] = t[tx][ty+i] + bias[c0+ty+i];
}

extern "C" void kernel_launch(void* const* d_in, const int* in_sizes, int n_in,
                              void* d_out, int out_size, void* d_ws, size_t ws_size,
                              hipStream_t stream){
  (void)in_sizes; (void)n_in; (void)out_size;
  const float* x   = (const float*)d_in[0];
  const float* ow1 = (const float*)d_in[1];
  const float* ob1 = (const float*)d_in[2];
  const float* w1  = (const float*)d_in[3];
  const float* b1  = (const float*)d_in[4];
  const float* ow2 = (const float*)d_in[5];
  const float* ob2 = (const float*)d_in[6];
  const float* w2  = (const float*)d_in[7];
  const float* b2  = (const float*)d_in[8];
  const float* ow3 = (const float*)d_in[9];
  const float* ob3 = (const float*)d_in[10];
  const float* w3  = (const float*)d_in[11];
  const float* b3  = (const float*)d_in[12];

  char* p = (char*)d_ws;
  auto carve = [&](size_t bytes)->char*{ char* r = p; p += (bytes + 255) & ~(size_t)255; return r; };
  _Float16* xh  = (_Float16*)carve((size_t)PTOT*64*2);
  _Float16* y1  = (_Float16*)carve((size_t)PTOT*64*2);
  _Float16* y2  = (_Float16*)carve((size_t)PTOT*512*2);
  _Float16* owT = (_Float16*)carve((size_t)9*32*512*2);
  _Float16* wT  = (_Float16*)carve((size_t)9*512*512*2);
  float*    om  = (float*)carve((size_t)3*PTOT*32*4);
  float*    pym = (float*)carve((size_t)PTOT*9*3*4);
  bool splitK = ws_size >= ((size_t)p - (size_t)d_ws) + (size_t)3*PTOT*256*4 + 4096;
  float* part = splitK ? (float*)carve((size_t)3*PTOT*256*4) : nullptr;

  k_nchw2nhwc<<<dim3(288,2,BBATCH), dim3(32,8), 0, stream>>>(x, xh);

  if(splitK){
    // ---- layer 1: 64 -> 64 (split-K gmain fp32 partials, z-folded + redA) ----
    k_twx<64,64><<<(9*32*64 + 9*64*64 + 255)/256,256,0,stream>>>(ow1, w1, owT, wT);
    k_goffs<64,3><<<dim3(PTOT/64,3),256,0,stream>>>(xh, owT, om);
    k_prep<3><<<(PTOT*9+255)/256,256,0,stream>>>(om, ob1, pym);
    k_gmain<64,64,64,1><<<dim3(3*PTOT/64,1,1),256,0,stream>>>(xh, pym, wT, b1, part);
    k_redA<64><<<(PTOT*64/4+255)/256,256,0,stream>>>(part, b1, y1);

    // ---- layer 2: 64 -> 512 (split goffs, direct gmain) ----
    k_twx<64,512><<<(9*32*64 + 9*512*64 + 255)/256,256,0,stream>>>(ow2, w2, owT, wT);
    k_goffs<64,3><<<dim3(PTOT/64,3),256,0,stream>>>(y1, owT, om);
    k_prep<3><<<(PTOT*9+255)/256,256,0,stream>>>(om, ob2, pym);
    k_gmain<64,512,256,0><<<dim3(PTOT/64,2),256,0,stream>>>(y1, pym, wT, b2, y2);

    // ---- layer 3: 512 -> 256 (BM=128 z-folded goffs + gmain f16 partials + redT) ----
    k_twx<512,256><<<(9*32*512 + 9*256*512 + 255)/256,256,0,stream>>>(ow3, w3, owT, wT);
    k_goffs<512,3><<<dim3(3*PTOT/128,1),256,0,stream>>>(y2, owT, om);
    k_prep<3><<<(PTOT*9+255)/256,256,0,stream>>>(om, ob3, pym);
    k_gmain<512,256,256,2><<<dim3(3*PTOT/64,1,1),256,0,stream>>>(y2, pym, wT, b3, part);
    k_redT<<<dim3(288,8,4),dim3(32,8),0,stream>>>((const _Float16*)part, b3, (float*)d_out);
  } else {
    // ---- fallback: non-split path ----
    k_twx<64,64><<<(9*32*64 + 9*64*64 + 255)/256,256,0,stream>>>(ow1, w1, owT, wT);
    k_goffs<64,9><<<dim3(PTOT/64,1),256,0,stream>>>(xh, owT, om);
    k_prep<1><<<(PTOT*9+255)/256,256,0,stream>>>(om, ob1, pym);
    k_gmain<64,64,64,0><<<dim3(PTOT/64,1),256,0,stream>>>(xh, pym, wT, b1, y1);

    k_twx<64,512><<<(9*32*64 + 9*512*64 + 255)/256,256,0,stream>>>(ow2, w2, owT, wT);
    k_goffs<64,9><<<dim3(PTOT/64,1),256,0,stream>>>(y1, owT, om);
    k_prep<1><<<(PTOT*9+255)/256,256,0,stream>>>(om, ob2, pym);
    k_gmain<64,512,256,0><<<dim3(PTOT/64,2),256,0,stream>>>(y1, pym, wT, b2, y2);

    k_twx<512,256><<<(9*32*512 + 9*256*512 + 255)/256,256,0,stream>>>(ow3, w3, owT, wT);
    k_goffs<512,9><<<dim3(PTOT/128,1),256,0,stream>>>(y2, owT, om);
    k_prep<1><<<(PTOT*9+255)/256,256,0,stream>>>(om, ob3, pym);
    k_gmain<512,256,256,0><<<dim3(PTOT/64,1),256,0,stream>>>(y2, pym, wT, b3, y1);
    {
      struct L { static __global__ void tr(const _Float16* in, float* out){
        int i = blockIdx.x*256 + threadIdx.x;
        if(i >= PTOT*256) return;
        int c = i & 255, pnt = i >> 8;
        int bb = pnt / HWP, pr = pnt % HWP;
        out[((size_t)bb*256 + c)*HWP + pr] = (float)in[i];
      }};
      hipLaunchKernelGGL(L::tr, dim3((PTOT*256+255)/256), dim3(256), 0, stream,
                         (const _Float16*)y1, (float*)d_out);
    }
  }
}

// Round 15
// 362.638 us; speedup vs baseline: 1.0300x; 1.0300x over previous
//
#include <hip/hip_runtime.h>
#include <stdint.h>

// DCNv2 x3 for MI355X. fp32 I/O, fp16 internal + MFMA f16.
// R24 = R22 (best, 364.4us) + y-fold for L2 gmain + nodrain in SPT==1 path.
//       R23 post-mortem: BM=128 goffs regressed (+15us: grid 864 -> sched
//       tail at 2 blk/CU, fewer load-issuing threads/row) -> goffs reverted
//       to R22's BM=64 pipelined version.
//       New: (1) MODE 0 gmain folds the BN-split (blockIdx.y) into bx with
//       the bijective XCD swizzle -- the 2 y-blocks of one position tile
//       gather the SAME corners; y-major dispatch made the 2nd sweep miss
//       L2 (same pathology z-fold fixed in R14/R19). Now temporally
//       adjacent -> L2 hits. (2) SPT==1 path gets R21's nodrain barrier.
//       Everything else R22-verbatim.

#define HH 96
#define WW 96
#define BBATCH 4
#define HWP (HH*WW)        // 9216
#define PTOT (BBATCH*HWP)  // 36864

typedef _Float16 f16x8 __attribute__((ext_vector_type(8)));
typedef _Float16 h2    __attribute__((ext_vector_type(2)));
typedef float f32x4 __attribute__((ext_vector_type(4)));

union U16x8 { uint4 q; _Float16 h[8]; h2 v[4]; };
union UB    { uint4 q; f16x8 f; };
union UH4   { uint2 d; _Float16 h[4]; };

__device__ __forceinline__ void barrier_nodrain(){
  asm volatile("s_waitcnt lgkmcnt(0)" ::: "memory");
  __builtin_amdgcn_s_barrier();
  __builtin_amdgcn_sched_barrier(0);
}

// ---- NCHW(f32, C=64) -> NHWC(f16) ----
__global__ void k_nchw2nhwc(const float* __restrict__ in, _Float16* __restrict__ out){
  __shared__ float t[32][33];
  int b = blockIdx.z;
  int p0 = blockIdx.x*32, c0 = blockIdx.y*32;
  int tx = threadIdx.x, ty = threadIdx.y; // 32x8
  #pragma unroll
  for(int i=0;i<32;i+=8)
    t[ty+i][tx] = in[((size_t)(b*64 + c0+ty+i))*HWP + p0+tx];
  __syncthreads();
  #pragma unroll
  for(int i=0;i<32;i+=8)
    out[((size_t)(b*HWP + p0+ty+i))*64 + c0+tx] = (_Float16)t[tx][ty+i];
}

// ---- fused weight transforms ----
template<int CIN,int COUT>
__global__ void k_twx(const float* __restrict__ ow, const float* __restrict__ w,
                      _Float16* __restrict__ owT, _Float16* __restrict__ wTf){
  int i = blockIdx.x*256 + threadIdx.x;
  constexpr int N1 = 9*32*CIN;
  constexpr int N2 = 9*COUT*CIN;
  if(i < N1){
    int c = i % CIN; int j = (i/CIN)&31; int k = i/(CIN*32);
    owT[i] = (j<27) ? (_Float16)ow[((size_t)(j*CIN + c))*9 + k] : (_Float16)0.f;
  } else if(i < N1+N2){
    int i2 = i - N1;
    int c = i2 % CIN; int o = (i2/CIN)%COUT; int k = i2/(CIN*COUT);
    int g = c>>5, quad = (c>>3)&3, j = c&7;
    int ob = o>>4, l15 = o&15;
    size_t dst = ((((size_t)k*(CIN/32) + g)*(COUT/16) + ob)*64 + quad*16 + l15)*8 + j;
    wTf[dst] = (_Float16)w[((size_t)(o*CIN + c))*9 + k];
  }
}

// ---- offset conv GEMM, NT taps per block (R22/R19 BM=64 version).
//      CIN>=128: pipelined spill-free + z-fold dispatch + nodrain barriers.
//      CIN==64: R6 verbatim (blockIdx.y = tap-group). ----
template<int CIN,int NT>
__launch_bounds__(256,2)
__global__ void k_goffs(const _Float16* __restrict__ xin, const _Float16* __restrict__ owT,
                        float* __restrict__ om){
  int t = threadIdx.x;
  int lane = t&63, wave = t>>6;
  int quad = lane>>4, l15 = lane&15;
  f32x4 acc[2] = {};
  int pos0, K0;
  float* omo;

  if constexpr (CIN >= 128){
    constexpr int NZ = (NT==3) ? 3 : 1;   // gridDim.x%8==0, (gridDim.x/8)%NZ==0
    int bx = blockIdx.x;
    int q = bx>>3, r = bx&7;
    int z = q - (q/NZ)*NZ;                // q % NZ
    int lin = r*((gridDim.x>>3)/NZ) + q/NZ;
    pos0 = lin*64;
    K0 = z*NT;
    omo = om + (size_t)z*PTOT*32;

    constexpr int SPT = CIN/64;     // stagings per tap
    constexpr int S = NT*SPT;       // total stagings (even)
    __shared__ __align__(16) _Float16 As[2][64*72];
    __shared__ __align__(16) _Float16 Bs[2][32*72];
    int pa = t>>2, ca = (t&3)*16;   // A: 64 pos x 16 ch/thread
    int jb = t>>3, cb = (t&7)*8;    // B: 32 rows x 8 ch/thread
    int P = pos0 + pa;
    int b = P/HWP, rem = P%HWP;
    int y = rem/WW, x = rem%WW;
    const _Float16* baseA = xin + (size_t)b*HWP*CIN + ca;
    const uint4 zz = make_uint4(0,0,0,0);
    int ofsC, ofsN = 0; bool vldC, vldN = false; int ktC, ktN = 0;
    {
      int iy = y + K0/3 - 1, ix = x + K0%3 - 1;
      vldC = (iy>=0)&&(iy<HH)&&(ix>=0)&&(ix<WW);
      int cy = min(max(iy,0),HH-1), cx = min(max(ix,0),WW-1);
      ofsC = (cy*WW+cx)*CIN; ktC = K0;
    }
    {
      uint4 a0 = vldC ? *(const uint4*)(baseA + ofsC)     : zz;
      uint4 a1 = vldC ? *(const uint4*)(baseA + ofsC + 8) : zz;
      uint4 bv = *(const uint4*)(owT + ((size_t)ktC*32 + jb)*CIN + cb);
      *(uint4*)&As[0][pa*72 + ca]     = a0;
      *(uint4*)&As[0][pa*72 + ca + 8] = a1;
      *(uint4*)&Bs[0][jb*72 + cb]     = bv;
    }
    uint4 nA0 = vldC ? *(const uint4*)(baseA + ofsC + 64)     : zz;
    uint4 nA1 = vldC ? *(const uint4*)(baseA + ofsC + 64 + 8) : zz;
    uint4 nAb = *(const uint4*)(owT + ((size_t)ktC*32 + jb)*CIN + 64 + cb);
    uint4 nB0, nB1, nBb;
    int buf = 0;

    #pragma unroll 1
    for(int ss=0; ss<S; ss+=2){
      {
        const int s = ss;
        barrier_nodrain();                // As/Bs[buf] visible; loads ride
        if(s > 0 && (s % SPT) == 0){ ofsC=ofsN; vldC=vldN; ktC=ktN; }
        if(s+2 < S){
          int sm2 = (s+2) % SPT;
          if(sm2 == 0){
            int k = K0 + (s+2)/SPT;
            int iy = y + k/3 - 1, ix = x + k%3 - 1;
            vldN = (iy>=0)&&(iy<HH)&&(ix>=0)&&(ix<WW);
            int cy = min(max(iy,0),HH-1), cx = min(max(ix,0),WW-1);
            ofsN = (cy*WW+cx)*CIN; ktN = k;
          }
          bool useN = (sm2 < 2);
          int ofs = useN ? ofsN : ofsC;
          bool vld = useN ? vldN : vldC;
          int kt  = useN ? ktN  : ktC;
          int c0 = sm2*64;
          nB0 = vld ? *(const uint4*)(baseA + ofs + c0)     : zz;
          nB1 = vld ? *(const uint4*)(baseA + ofs + c0 + 8) : zz;
          nBb = *(const uint4*)(owT + ((size_t)kt*32 + jb)*CIN + c0 + cb);
        }
        UB afu0, afu1;
        afu0.q = *(const uint4*)&As[buf][(wave*16 + l15)*72 + quad*8];
        afu1.q = *(const uint4*)&As[buf][(wave*16 + l15)*72 + 32 + quad*8];
        #pragma unroll
        for(int ni=0;ni<2;ni++){
          UB bu0, bu1;
          bu0.q = *(const uint4*)&Bs[buf][(ni*16 + l15)*72 + quad*8];
          bu1.q = *(const uint4*)&Bs[buf][(ni*16 + l15)*72 + 32 + quad*8];
          acc[ni] = __builtin_amdgcn_mfma_f32_16x16x32_f16(afu0.f, bu0.f, acc[ni], 0,0,0);
          acc[ni] = __builtin_amdgcn_mfma_f32_16x16x32_f16(afu1.f, bu1.f, acc[ni], 0,0,0);
        }
        if(s+1 < S){
          *(uint4*)&As[buf^1][pa*72 + ca]     = nA0;
          *(uint4*)&As[buf^1][pa*72 + ca + 8] = nA1;
          *(uint4*)&Bs[buf^1][jb*72 + cb]     = nAb;
        }
        buf ^= 1;
      }
      {
        const int s = ss+1;
        barrier_nodrain();
        if((s % SPT) == 0){ ofsC=ofsN; vldC=vldN; ktC=ktN; }
        if(s+2 < S){
          int sm2 = (s+2) % SPT;
          if(sm2 == 0){
            int k = K0 + (s+2)/SPT;
            int iy = y + k/3 - 1, ix = x + k%3 - 1;
            vldN = (iy>=0)&&(iy<HH)&&(ix>=0)&&(ix<WW);
            int cy = min(max(iy,0),HH-1), cx = min(max(ix,0),WW-1);
            ofsN = (cy*WW+cx)*CIN; ktN = k;
          }
          bool useN = (sm2 < 2);
          int ofs = useN ? ofsN : ofsC;
          bool vld = useN ? vldN : vldC;
          int kt  = useN ? ktN  : ktC;
          int c0 = sm2*64;
          nA0 = vld ? *(const uint4*)(baseA + ofs + c0)     : zz;
          nA1 = vld ? *(const uint4*)(baseA + ofs + c0 + 8) : zz;
          nAb = *(const uint4*)(owT + ((size_t)kt*32 + jb)*CIN + c0 + cb);
        }
        UB afu0, afu1;
        afu0.q = *(const uint4*)&As[buf][(wave*16 + l15)*72 + quad*8];
        afu1.q = *(const uint4*)&As[buf][(wave*16 + l15)*72 + 32 + quad*8];
        #pragma unroll
        for(int ni=0;ni<2;ni++){
          UB bu0, bu1;
          bu0.q = *(const uint4*)&Bs[buf][(ni*16 + l15)*72 + quad*8];
          bu1.q = *(const uint4*)&Bs[buf][(ni*16 + l15)*72 + 32 + quad*8];
          acc[ni] = __builtin_amdgcn_mfma_f32_16x16x32_f16(afu0.f, bu0.f, acc[ni], 0,0,0);
          acc[ni] = __builtin_amdgcn_mfma_f32_16x16x32_f16(afu1.f, bu1.f, acc[ni], 0,0,0);
        }
        if(s+1 < S){
          *(uint4*)&As[buf^1][pa*72 + ca]     = nB0;
          *(uint4*)&As[buf^1][pa*72 + ca + 8] = nB1;
          *(uint4*)&Bs[buf^1][jb*72 + cb]     = nBb;
        }
        buf ^= 1;
      }
    }
  } else {
    // ---- R6 verbatim path (CIN==64) ----
    pos0 = blockIdx.x*64;
    K0 = blockIdx.y*NT;
    omo = om + (size_t)blockIdx.y*PTOT*32;
    __shared__ __align__(16) _Float16 As[64*40];
    __shared__ __align__(16) _Float16 Bs[32*40];
    int pa = t>>2, ca = (t&3)*8;
    int P = pos0 + pa;
    int b = P/HWP, rem = P%HWP;
    int y = rem/WW, x = rem%WW;
    #pragma unroll 1
    for(int k=K0;k<K0+NT;k++){
      int iy = y + k/3 - 1, ix = x + k%3 - 1;
      bool valid = (iy>=0)&&(iy<HH)&&(ix>=0)&&(ix<WW);
      const _Float16* src = xin + (((size_t)b*HWP + iy*WW + ix)*CIN) + ca;
      #pragma unroll 1
      for(int c0=0;c0<CIN;c0+=32){
        uint4 av = make_uint4(0,0,0,0);
        if(valid) av = *(const uint4*)(src + c0);
        *(uint4*)&As[pa*40 + ca] = av;
        if(t < 128){
          int j = t>>2;
          *(uint4*)&Bs[j*40 + ca] = *(const uint4*)(owT + ((size_t)k*32 + j)*CIN + c0 + ca);
        }
        __syncthreads();
        UB afu; afu.q = *(const uint4*)&As[(wave*16 + l15)*40 + quad*8];
        #pragma unroll
        for(int ni=0;ni<2;ni++){
          UB bu; bu.q = *(const uint4*)&Bs[(ni*16 + l15)*40 + quad*8];
          acc[ni] = __builtin_amdgcn_mfma_f32_16x16x32_f16(afu.f, bu.f, acc[ni], 0,0,0);
        }
        __syncthreads();
      }
    }
  }

  #pragma unroll
  for(int ni=0;ni<2;ni++)
    #pragma unroll
    for(int r=0;r<4;r++){
      int row = wave*16 + quad*4 + r;
      omo[(size_t)(pos0+row)*32 + ni*16 + l15] = acc[ni][r];
    }
}

// ---- per-(p,k) sampling params; sums NS om slabs (R6 verbatim) ----
template<int NS>
__global__ void k_prep(const float* __restrict__ om, const float* __restrict__ ob,
                       float* __restrict__ pym){
  int i = blockIdx.x*256 + threadIdx.x;
  if(i >= PTOT*9) return;
  int k = i%9, p = i/9;
  int rem = p%HWP;
  int y = rem/WW, x = rem%WW;
  float oy=0.f, ox=0.f, mm=0.f;
  #pragma unroll
  for(int s=0;s<NS;s++){
    const float* o = om + (size_t)s*PTOT*32 + (size_t)p*32;
    oy += o[2*k]; ox += o[2*k+1]; mm += o[18+k];
  }
  oy += ob[2*k]; ox += ob[2*k+1]; mm += ob[18+k];
  float m = 1.f/(1.f + expf(-mm));
  pym[(size_t)i*3+0] = (float)(y + k/3 - 1) + oy;
  pym[(size_t)i*3+1] = (float)(x + k%3 - 1) + ox;
  pym[(size_t)i*3+2] = m;
}

// ---- main DCN GEMM: R22 structure + y-fold for MODE 0 + nodrain everywhere.
//      SPT>1 (CIN=512): 2-deep corner prefetch. SPT==1: 1-deep.
//      MODE 0: 9 taps, f16 NHWC out (+bias); BN-split (NY=COUT/BN) folded
//              into blockIdx.x (y-blocks of one tile temporally adjacent).
//      MODE 1: 3 taps (z folded in bx), fp32 partial out (no bias).
//      MODE 2: 3 taps (z folded in bx), f16 partial out (no bias).
template<int CIN,int COUT,int BN,int MODE>
__launch_bounds__(256,2)
__global__ void k_gmain(const _Float16* __restrict__ xin, const float* __restrict__ pym,
                        const _Float16* __restrict__ wTf, const float* __restrict__ bias,
                        void* __restrict__ outv){
  constexpr int NW = BN/4;      // per-wave N width
  constexpr int NF = NW/16;     // n-frags per wave
  constexpr int KG = CIN/32;    // K-groups
  constexpr int OB = COUT/16;   // o-blocks
  constexpr int SPT = CIN/64;   // stagings per tap
  constexpr int NY = (MODE==0) ? (COUT/BN) : 1;  // BN-splits folded into bx
  constexpr int NZ = (MODE>=1) ? 3 : NY;  // folds in grid.x
  constexpr int KN = (MODE>=1) ? 3 : 9;
  constexpr int S = KN*SPT;     // total stagings
  __shared__ __align__(16) _Float16 As[2][64*72];   // 64 pos x 64ch, stride 72
  int bx = blockIdx.x;
  // bijective XCD swizzle + fold: gridDim.x % 8 == 0, (gridDim.x/8) % NZ == 0
  int q = bx>>3, r = bx&7;
  int z = q - (q/NZ)*NZ;                       // q % NZ
  int lin = r*((gridDim.x>>3)/NZ) + q/NZ;      // contiguous chunk per XCD
  int pos0 = lin*64;
  int o0 = (MODE==0) ? z*BN : 0;
  int K0 = (MODE>=1) ? z*3 : 0;
  int t = threadIdx.x;
  int lane = t&63, wave = t>>6;
  int quad = lane>>4, l15 = lane&15;
  f32x4 acc[4][NF] = {};
  int pa = t>>2, ca = (t&3)*16;   // 16 channels per thread
  int P = pos0 + pa;
  int b = P/HWP;
  const _Float16* base = xin + (size_t)b*HWP*CIN + ca;
  const uint4* wf = (const uint4*)wTf;
  int obBase = (o0>>4) + wave*NF;

  auto tapParams = [&](int k, h2* W, int* oc){
    const float* pp = pym + ((size_t)P*9 + k)*3;
    float py = pp[0], px = pp[1], mk = pp[2];
    float y0f = floorf(py), x0f = floorf(px);
    float wy = py - y0f, wx = px - x0f;
    int iy0 = (int)y0f, ix0 = (int)x0f;
    int iy1 = iy0+1, ix1 = ix0+1;
    bool vy0 = (iy0>=0)&&(iy0<HH), vy1 = (iy1>=0)&&(iy1<HH);
    bool vx0 = (ix0>=0)&&(ix0<WW), vx1 = (ix1>=0)&&(ix1<WW);
    float w00 = (vy0&&vx0) ? (1.f-wy)*(1.f-wx)*mk : 0.f;
    float w01 = (vy0&&vx1) ? (1.f-wy)*wx*mk      : 0.f;
    float w10 = (vy1&&vx0) ? wy*(1.f-wx)*mk      : 0.f;
    float w11 = (vy1&&vx1) ? wy*wx*mk            : 0.f;
    int cy0 = min(max(iy0,0),HH-1), cy1 = min(max(iy1,0),HH-1);
    int cx0 = min(max(ix0,0),WW-1), cx1 = min(max(ix1,0),WW-1);
    W[0] = h2{(_Float16)w00,(_Float16)w00};
    W[1] = h2{(_Float16)w01,(_Float16)w01};
    W[2] = h2{(_Float16)w10,(_Float16)w10};
    W[3] = h2{(_Float16)w11,(_Float16)w11};
    oc[0] = (cy0*WW+cx0)*CIN;
    oc[1] = (cy0*WW+cx1)*CIN;
    oc[2] = (cy1*WW+cx0)*CIN;
    oc[3] = (cy1*WW+cx1)*CIN;
  };

  // B(s) linear address: idx = (K0 + s/SPT)*KG + 2*(s%SPT) = K0*KG + 2*s
  uint4 Bq[2][NF];
  const uint4* wB = wf + (size_t)(K0*KG)*OB*64 + lane;
  int buf = 0;

  if constexpr (SPT > 1){
    // ================= 2-deep corner-prefetch path (CIN=512) =================
    h2 Wcur[4], Wnxt[4];
    int ocCur[4], ocNxt[4];
    tapParams(K0, Wcur, ocCur);
    U16x8 ncA[4][2], ncB[4][2];
    // prologue: produce staging 0; load B(0); issue corners(1) -> ncA
    {
      U16x8 c0v[4][2];
      #pragma unroll
      for(int c=0;c<4;c++){
        const _Float16* pp = base + ocCur[c];
        c0v[c][0].q = *(const uint4*)(pp);
        c0v[c][1].q = *(const uint4*)(pp + 8);
      }
      #pragma unroll
      for(int ks=0;ks<2;ks++)
        #pragma unroll
        for(int ni=0;ni<NF;ni++)
          Bq[ks][ni] = wB[(size_t)ks*OB*64 + (size_t)(obBase+ni)*64];
      wB += 2*OB*64;
      U16x8 rr0, rr1;
      #pragma unroll
      for(int j=0;j<4;j++){
        rr0.v[j] = c0v[0][0].v[j]*Wcur[0] + c0v[1][0].v[j]*Wcur[1] + c0v[2][0].v[j]*Wcur[2] + c0v[3][0].v[j]*Wcur[3];
        rr1.v[j] = c0v[0][1].v[j]*Wcur[0] + c0v[1][1].v[j]*Wcur[1] + c0v[2][1].v[j]*Wcur[2] + c0v[3][1].v[j]*Wcur[3];
      }
      *(uint4*)&As[0][pa*72 + ca]     = rr0.q;
      *(uint4*)&As[0][pa*72 + ca + 8] = rr1.q;
      // corners for staging 1 (tap 0, c0=64)
      #pragma unroll
      for(int c=0;c<4;c++){
        const _Float16* pp = base + ocCur[c] + 64;
        ncA[c][0].q = *(const uint4*)(pp);
        ncA[c][1].q = *(const uint4*)(pp + 8);
      }
    }

    auto stage = [&](int s, U16x8 (&ncC)[4][2], U16x8 (&ncN)[4][2]){
      barrier_nodrain();                   // As[buf] visible; loads ride
      bool more  = (s+1 < S);
      bool more2 = (s+2 < S);
      if(s > 0 && (s % SPT) == 0){
        #pragma unroll
        for(int j=0;j<4;j++){ Wcur[j]=Wnxt[j]; ocCur[j]=ocNxt[j]; }
      }
      if(more2){
        int sm2 = (s+2) % SPT;
        if(sm2 == 0) tapParams(K0 + (s+2)/SPT, Wnxt, ocNxt);
        bool useNxt = (sm2 < 2);
        int ocS[4];
        #pragma unroll
        for(int c=0;c<4;c++) ocS[c] = useNxt ? ocNxt[c] : ocCur[c];
        int c0 = sm2*64;
        #pragma unroll
        for(int c=0;c<4;c++){
          const _Float16* pp = base + ocS[c] + c0;
          ncN[c][0].q = *(const uint4*)(pp);
          ncN[c][1].q = *(const uint4*)(pp + 8);
        }
      }
      UB afu[2][4];
      #pragma unroll
      for(int ks=0;ks<2;ks++)
        #pragma unroll
        for(int mi=0;mi<4;mi++)
          afu[ks][mi].q = *(const uint4*)&As[buf][(mi*16 + l15)*72 + ks*32 + quad*8];
      #pragma unroll
      for(int ks=0;ks<2;ks++)
        #pragma unroll
        for(int ni=0;ni<NF;ni++){
          UB bu; bu.q = Bq[ks][ni];
          #pragma unroll
          for(int mi=0;mi<4;mi++)
            acc[mi][ni] = __builtin_amdgcn_mfma_f32_16x16x32_f16(afu[ks][mi].f, bu.f, acc[mi][ni], 0,0,0);
        }
      if(more){
        #pragma unroll
        for(int ks=0;ks<2;ks++)
          #pragma unroll
          for(int ni=0;ni<NF;ni++)
            Bq[ks][ni] = wB[(size_t)ks*OB*64 + (size_t)(obBase+ni)*64];
        wB += 2*OB*64;
        bool lerpNxt = (((s+1) % SPT) == 0);
        h2 Wl[4];
        #pragma unroll
        for(int j=0;j<4;j++) Wl[j] = lerpNxt ? Wnxt[j] : Wcur[j];
        U16x8 rr0, rr1;
        #pragma unroll
        for(int j=0;j<4;j++){
          rr0.v[j] = ncC[0][0].v[j]*Wl[0] + ncC[1][0].v[j]*Wl[1] + ncC[2][0].v[j]*Wl[2] + ncC[3][0].v[j]*Wl[3];
          rr1.v[j] = ncC[0][1].v[j]*Wl[0] + ncC[1][1].v[j]*Wl[1] + ncC[2][1].v[j]*Wl[2] + ncC[3][1].v[j]*Wl[3];
        }
        *(uint4*)&As[buf^1][pa*72 + ca]     = rr0.q;
        *(uint4*)&As[buf^1][pa*72 + ca + 8] = rr1.q;
      }
      buf ^= 1;
    };

    #pragma unroll 1
    for(int ss=0; ss<S; ss+=2){   // S even for all CIN=512 instantiations
      stage(ss,   ncA, ncB);
      stage(ss+1, ncB, ncA);
    }
  } else {
    // ================= 1-deep path (CIN=64) + nodrain =================
    h2 Wc[4]; int oc_[4];
    h2 Wn[4]; int ocn[4];
    tapParams(K0, Wc, oc_);
    {
      U16x8 nc[4][2];
      #pragma unroll
      for(int c=0;c<4;c++){
        const _Float16* pp = base + oc_[c];
        nc[c][0].q = *(const uint4*)(pp);
        nc[c][1].q = *(const uint4*)(pp + 8);
      }
      #pragma unroll
      for(int ks=0;ks<2;ks++)
        #pragma unroll
        for(int ni=0;ni<NF;ni++)
          Bq[ks][ni] = wB[(size_t)ks*OB*64 + (size_t)(obBase+ni)*64];
      wB += 2*OB*64;
      U16x8 rr0, rr1;
      #pragma unroll
      for(int j=0;j<4;j++){
        rr0.v[j] = nc[0][0].v[j]*Wc[0] + nc[1][0].v[j]*Wc[1] + nc[2][0].v[j]*Wc[2] + nc[3][0].v[j]*Wc[3];
        rr1.v[j] = nc[0][1].v[j]*Wc[0] + nc[1][1].v[j]*Wc[1] + nc[2][1].v[j]*Wc[2] + nc[3][1].v[j]*Wc[3];
      }
      *(uint4*)&As[0][pa*72 + ca]     = rr0.q;
      *(uint4*)&As[0][pa*72 + ca + 8] = rr1.q;
    }
    if(S>1) tapParams(K0+1, Wn, ocn);

    #pragma unroll 1
    for(int s=0;s<S;s++){
      barrier_nodrain();
      U16x8 nc[4][2];
      bool more = (s+1 < S);
      if(more){
        #pragma unroll
        for(int c=0;c<4;c++){ Wc[c]=Wn[c]; oc_[c]=ocn[c]; }
        #pragma unroll
        for(int c=0;c<4;c++){
          const _Float16* pp = base + oc_[c];
          nc[c][0].q = *(const uint4*)(pp);
          nc[c][1].q = *(const uint4*)(pp + 8);
        }
      }
      UB afu[2][4];
      #pragma unroll
      for(int ks=0;ks<2;ks++)
        #pragma unroll
        for(int mi=0;mi<4;mi++)
          afu[ks][mi].q = *(const uint4*)&As[buf][(mi*16 + l15)*72 + ks*32 + quad*8];
      #pragma unroll
      for(int ks=0;ks<2;ks++)
        #pragma unroll
        for(int ni=0;ni<NF;ni++){
          UB bu; bu.q = Bq[ks][ni];
          #pragma unroll
          for(int mi=0;mi<4;mi++)
            acc[mi][ni] = __builtin_amdgcn_mfma_f32_16x16x32_f16(afu[ks][mi].f, bu.f, acc[mi][ni], 0,0,0);
        }
      if(more){
        #pragma unroll
        for(int ks=0;ks<2;ks++)
          #pragma unroll
          for(int ni=0;ni<NF;ni++)
            Bq[ks][ni] = wB[(size_t)ks*OB*64 + (size_t)(obBase+ni)*64];
        wB += 2*OB*64;
        if(s+2 < S) tapParams(K0+s+2, Wn, ocn);
        U16x8 rr0, rr1;
        #pragma unroll
        for(int j=0;j<4;j++){
          rr0.v[j] = nc[0][0].v[j]*Wc[0] + nc[1][0].v[j]*Wc[1] + nc[2][0].v[j]*Wc[2] + nc[3][0].v[j]*Wc[3];
          rr1.v[j] = nc[0][1].v[j]*Wc[0] + nc[1][1].v[j]*Wc[1] + nc[2][1].v[j]*Wc[2] + nc[3][1].v[j]*Wc[3];
        }
        *(uint4*)&As[buf^1][pa*72 + ca]     = rr0.q;
        *(uint4*)&As[buf^1][pa*72 + ca + 8] = rr1.q;
      }
      buf ^= 1;
    }
  }

  #pragma unroll
  for(int mi=0;mi<4;mi++){
    #pragma unroll
    for(int ni=0;ni<NF;ni++){
      int col = o0 + wave*NW + ni*16 + l15;
      if(MODE==1){
        float* out = (float*)outv + (size_t)z*PTOT*COUT;
        #pragma unroll
        for(int r2=0;r2<4;r2++){
          int row = pos0 + mi*16 + quad*4 + r2;
          out[(size_t)row*COUT + col] = acc[mi][ni][r2];
        }
      } else if(MODE==2){
        _Float16* out = (_Float16*)outv + (size_t)z*PTOT*COUT;
        #pragma unroll
        for(int r2=0;r2<4;r2++){
          int row = pos0 + mi*16 + quad*4 + r2;
          out[(size_t)row*COUT + col] = (_Float16)acc[mi][ni][r2];
        }
      } else {
        float bo = bias[col];
        _Float16* out = (_Float16*)outv;
        #pragma unroll
        for(int r2=0;r2<4;r2++){
          int row = pos0 + mi*16 + quad*4 + r2;
          out[(size_t)row*COUT + col] = (_Float16)(acc[mi][ni][r2]+bo);
        }
      }
    }
  }
}

// ---- reduce 3 fp32 partial slabs -> f16 NHWC (+bias) ----
template<int COUT>
__global__ void k_redA(const float* __restrict__ part, const float* __restrict__ bias,
                       _Float16* __restrict__ out){
  int i4 = blockIdx.x*256 + threadIdx.x;
  constexpr int N4 = PTOT*COUT/4;
  if(i4 >= N4) return;
  const float4* p = (const float4*)part;
  float4 a = p[i4], b = p[i4 + N4], c = p[i4 + 2*N4];
  int col0 = (i4*4) & (COUT-1);
  float4 bi = *(const float4*)(bias + col0);
  UH4 r;
  r.h[0] = (_Float16)(a.x+b.x+c.x+bi.x);
  r.h[1] = (_Float16)(a.y+b.y+c.y+bi.y);
  r.h[2] = (_Float16)(a.z+b.z+c.z+bi.z);
  r.h[3] = (_Float16)(a.w+b.w+c.w+bi.w);
  *(uint2*)(out + (size_t)i4*4) = r.d;
}

// ---- reduce 3 f16 partial slabs [P][256] -> fp32 NCHW (+bias), LDS transpose ----
__global__ void k_redT(const _Float16* __restrict__ part, const float* __restrict__ bias,
                       float* __restrict__ out){
  __shared__ float t[32][33];
  constexpr int COUT = 256;
  constexpr size_t SL = (size_t)PTOT*COUT;
  int b = blockIdx.z;
  int p0 = blockIdx.x*32, c0 = blockIdx.y*32;
  int tx = threadIdx.x, ty = threadIdx.y; // 32x8
  #pragma unroll
  for(int i=0;i<32;i+=8){
    size_t idx = ((size_t)(b*HWP + p0+ty+i))*COUT + c0+tx;
    t[ty+i][tx] = (float)part[idx] + (float)part[idx+SL] + (float)part[idx+2*SL];
  }
  __syncthreads();
  #pragma unroll
  for(int i=0;i<32;i+=8)
    out[((size_t)(b*COUT + c0+ty+i))*HWP + p0+tx] = t[tx][ty+i] + bias[c0+ty+i];
}

extern "C" void kernel_launch(void* const* d_in, const int* in_sizes, int n_in,
                              void* d_out, int out_size, void* d_ws, size_t ws_size,
                              hipStream_t stream){
  (void)in_sizes; (void)n_in; (void)out_size;
  const float* x   = (const float*)d_in[0];
  const float* ow1 = (const float*)d_in[1];
  const float* ob1 = (const float*)d_in[2];
  const float* w1  = (const float*)d_in[3];
  const float* b1  = (const float*)d_in[4];
  const float* ow2 = (const float*)d_in[5];
  const float* ob2 = (const float*)d_in[6];
  const float* w2  = (const float*)d_in[7];
  const float* b2  = (const float*)d_in[8];
  const float* ow3 = (const float*)d_in[9];
  const float* ob3 = (const float*)d_in[10];
  const float* w3  = (const float*)d_in[11];
  const float* b3  = (const float*)d_in[12];

  char* p = (char*)d_ws;
  auto carve = [&](size_t bytes)->char*{ char* r = p; p += (bytes + 255) & ~(size_t)255; return r; };
  _Float16* xh  = (_Float16*)carve((size_t)PTOT*64*2);
  _Float16* y1  = (_Float16*)carve((size_t)PTOT*64*2);
  _Float16* y2  = (_Float16*)carve((size_t)PTOT*512*2);
  _Float16* owT = (_Float16*)carve((size_t)9*32*512*2);
  _Float16* wT  = (_Float16*)carve((size_t)9*512*512*2);
  float*    om  = (float*)carve((size_t)3*PTOT*32*4);
  float*    pym = (float*)carve((size_t)PTOT*9*3*4);
  bool splitK = ws_size >= ((size_t)p - (size_t)d_ws) + (size_t)3*PTOT*256*4 + 4096;
  float* part = splitK ? (float*)carve((size_t)3*PTOT*256*4) : nullptr;

  k_nchw2nhwc<<<dim3(288,2,BBATCH), dim3(32,8), 0, stream>>>(x, xh);

  if(splitK){
    // ---- layer 1: 64 -> 64 (split-K gmain fp32 partials, z-folded + redA) ----
    k_twx<64,64><<<(9*32*64 + 9*64*64 + 255)/256,256,0,stream>>>(ow1, w1, owT, wT);
    k_goffs<64,3><<<dim3(PTOT/64,3),256,0,stream>>>(xh, owT, om);
    k_prep<3><<<(PTOT*9+255)/256,256,0,stream>>>(om, ob1, pym);
    k_gmain<64,64,64,1><<<dim3(3*PTOT/64,1,1),256,0,stream>>>(xh, pym, wT, b1, part);
    k_redA<64><<<(PTOT*64/4+255)/256,256,0,stream>>>(part, b1, y1);

    // ---- layer 2: 64 -> 512 (split goffs, y-folded gmain) ----
    k_twx<64,512><<<(9*32*64 + 9*512*64 + 255)/256,256,0,stream>>>(ow2, w2, owT, wT);
    k_goffs<64,3><<<dim3(PTOT/64,3),256,0,stream>>>(y1, owT, om);
    k_prep<3><<<(PTOT*9+255)/256,256,0,stream>>>(om, ob2, pym);
    k_gmain<64,512,256,0><<<dim3(2*PTOT/64,1),256,0,stream>>>(y1, pym, wT, b2, y2);

    // ---- layer 3: 512 -> 256 (z-folded goffs + gmain f16 partials + redT) ----
    k_twx<512,256><<<(9*32*512 + 9*256*512 + 255)/256,256,0,stream>>>(ow3, w3, owT, wT);
    k_goffs<512,3><<<dim3(3*PTOT/64,1),256,0,stream>>>(y2, owT, om);
    k_prep<3><<<(PTOT*9+255)/256,256,0,stream>>>(om, ob3, pym);
    k_gmain<512,256,256,2><<<dim3(3*PTOT/64,1,1),256,0,stream>>>(y2, pym, wT, b3, part);
    k_redT<<<dim3(288,8,4),dim3(32,8),0,stream>>>((const _Float16*)part, b3, (float*)d_out);
  } else {
    // ---- fallback: non-split path ----
    k_twx<64,64><<<(9*32*64 + 9*64*64 + 255)/256,256,0,stream>>>(ow1, w1, owT, wT);
    k_goffs<64,9><<<dim3(PTOT/64,1),256,0,stream>>>(xh, owT, om);
    k_prep<1><<<(PTOT*9+255)/256,256,0,stream>>>(om, ob1, pym);
    k_gmain<64,64,64,0><<<dim3(PTOT/64,1),256,0,stream>>>(xh, pym, wT, b1, y1);

    k_twx<64,512><<<(9*32*64 + 9*512*64 + 255)/256,256,0,stream>>>(ow2, w2, owT, wT);
    k_goffs<64,9><<<dim3(PTOT/64,1),256,0,stream>>>(y1, owT, om);
    k_prep<1><<<(PTOT*9+255)/256,256,0,stream>>>(om, ob2, pym);
    k_gmain<64,512,256,0><<<dim3(2*PTOT/64,1),256,0,stream>>>(y1, pym, wT, b2, y2);

    k_twx<512,256><<<(9*32*512 + 9*256*512 + 255)/256,256,0,stream>>>(ow3, w3, owT, wT);
    k_goffs<512,9><<<dim3(PTOT/64,1),256,0,stream>>>(y2, owT, om);
    k_prep<1><<<(PTOT*9+255)/256,256,0,stream>>>(om, ob3, pym);
    k_gmain<512,256,256,0><<<dim3(PTOT/64,1),256,0,stream>>>(y2, pym, wT, b3, y1);
    {
      struct L { static __global__ void tr(const _Float16* in, float* out){
        int i = blockIdx.x*256 + threadIdx.x;
        if(i >= PTOT*256) return;
        int c = i & 255, pnt = i >> 8;
        int bb = pnt / HWP, pr = pnt % HWP;
        out[((size_t)bb*256 + c)*HWP + pr] = (float)in[i];
      }};
      hipLaunchKernelGGL(L::tr, dim3((PTOT*256+255)/256), dim3(256), 0, stream,
                         (const _Float16*)y1, (float*)d_out);
    }
  }
}